// Round 13
// baseline (702.948 us; speedup 1.0000x reference)
//
#include <hip/hip_runtime.h>
#include <cstdint>
#include <cstddef>

namespace {

constexpr int kH  = 1024;
constexpr int kB  = 64;
constexpr int kN  = 32;
constexpr int kT  = 400;
constexpr int kV  = 32000;
constexpr int kM  = kN * kB;   // 2048
constexpr int k3H = 3 * kH;    // 3072

typedef _Float16 f16;
typedef _Float16 f16x4 __attribute__((ext_vector_type(4)));
typedef _Float16 f16x8 __attribute__((ext_vector_type(8)));
typedef float    f32x4v __attribute__((ext_vector_type(4)));

__device__ __forceinline__ void gload_lds16(const void* g, void* l) {
  __builtin_amdgcn_global_load_lds((__attribute__((address_space(1))) void*)g,
                                   (__attribute__((address_space(3))) void*)l,
                                   16, 0, 0);
}

__device__ __forceinline__ uint32_t pack_f16x2(f16 lo, f16 hi) {
  union { f16 h[2]; uint32_t u; } c;
  c.h[0] = lo; c.h[1] = hi;
  return c.u;
}

// CTR page layout (u32 words; memset 8192B before pre_kernel):
//   [0..63]    gru per-block step flags
//   [64+32r]   conc[r]: concat tiles done for row r (target 8), r<16
//   [640..1663] u2 accumulator (1024 f32, atomicAdd by pre)
//   [1664]     biasS accumulator (f32)
constexpr int C_FLAGS = 0;
constexpr int C_CONC  = 64;    // stride 32 words (128B)
constexpr int C_U2    = 640;
constexpr int C_BS    = 1664;

// ---------------- fused pre-kernel: cvt Wih/Whh | gather | init | attn_prep ----------------

__global__ __launch_bounds__(256)
void pre_kernel(const float* __restrict__ Wih, f16* __restrict__ WihH,
                const float* __restrict__ Whh, f16* __restrict__ WhhH,
                const int* __restrict__ seq, const float* __restrict__ emb,
                f16* __restrict__ Xh, const float* __restrict__ lh,
                f16* __restrict__ HH0,
                const float* __restrict__ attnW, const float* __restrict__ attnB,
                const float* __restrict__ attnV, unsigned int* __restrict__ ctr) {
  const int bid = blockIdx.x, tid = threadIdx.x;
  if (bid < 512) {
    const float* src = (bid < 256) ? Wih : Whh;
    f16* dst = (bid < 256) ? WihH : WhhH;
    constexpr int n4 = k3H * kH / 4;
    for (int i = (bid & 255) * 256 + tid; i < n4; i += 256 * 256) {
      float4 v = reinterpret_cast<const float4*>(src)[i];
      f16x4 o = { (f16)v.x, (f16)v.y, (f16)v.z, (f16)v.w };
      reinterpret_cast<f16x4*>(dst)[i] = o;
    }
  } else if (bid < 640) {
    const int m0 = (bid - 512) * 16;
    for (int k = 0; k < 16; ++k) {
      const int m = m0 + k;
      const int tok = seq[m];
      float4 v = reinterpret_cast<const float4*>(emb + (size_t)tok * kH)[tid];
      f16x4 o = { (f16)v.x, (f16)v.y, (f16)v.z, (f16)v.w };
      reinterpret_cast<f16x4*>(Xh + (size_t)m * kH)[tid] = o;
    }
  } else if (bid < 644) {
    for (int i = (bid - 640) * 256 + tid; i < 16384; i += 1024) {
      float4 v = reinterpret_cast<const float4*>(lh)[i];
      f16x4 o = { (f16)v.x, (f16)v.y, (f16)v.z, (f16)v.w };
      reinterpret_cast<f16x4*>(HH0)[i] = o;
    }
  } else if (bid < 708) {
    // attn u2: coalesced rows, 64 blocks = 4 h-tiles x 16 k-chunks, atomicAdd
    const int b  = bid - 644;
    const int hc = b & 3;
    const int kc = b >> 2;
    const int h  = hc * 256 + tid;
    float sum = 0.0f;
    for (int k = kc * 64; k < kc * 64 + 64; ++k)
      sum += attnW[(size_t)k * (2 * kH) + kH + h] * attnV[k];
    atomicAdd(reinterpret_cast<float*>(ctr + C_U2) + h, sum);
  } else {
    if (tid < 64) {
      float s = 0.0f;
      for (int k = tid; k < kH; k += 64) s += attnB[k] * attnV[k];
      #pragma unroll
      for (int o = 32; o > 0; o >>= 1) s += __shfl_xor(s, o);
      if (tid == 0) atomicAdd(reinterpret_cast<float*>(ctr + C_BS), s);
    }
  }
}

// ---------------- proven 128x128 GEMM tile body (device) ----------------
// MODE 0: +bias, tanh -> f16 H2 via LDS repack + 8B write-through stores (N=kH)
// MODE 1: +bias -> f32 outC, plain scalar stores (N=kV)

template <int MODE>
__device__ void tile_gemm(f16* __restrict__ As, f16* __restrict__ Bs,
                          const f16* __restrict__ Ag0, const f16* __restrict__ Bg0,
                          const float* __restrict__ bias, void* __restrict__ Cout,
                          int N, int K, int m0, int n0) {
  const int tid  = threadIdx.x;
  const int wave = tid >> 6;
  const int lane = tid & 63;
  const int wm = (wave >> 1) * 64;
  const int wn = (wave & 1) * 64;
  const int rsub = lane >> 3;
  const int coff = (lane & 7) * 8;
  f32x4v acc[4][4] = {};
  const int nk = K >> 6;
  for (int kc = 0; kc < nk; ++kc) {
    const f16* Ag = Ag0 + kc * 64;
    const f16* Bg = Bg0 + kc * 64;
    for (int c = wave; c < 16; c += 4) {
      const int row = c * 8 + rsub;
      gload_lds16(Ag + (size_t)row * K + coff, &As[c * 512]);
      gload_lds16(Bg + (size_t)row * K + coff, &Bs[c * 512]);
    }
    __syncthreads();
    #pragma unroll
    for (int kk = 0; kk < 2; ++kk) {
      const int ko = kk * 32 + (lane >> 4) * 8;
      f16x8 af[4], bfr[4];
      #pragma unroll
      for (int i = 0; i < 4; ++i) {
        af[i]  = *reinterpret_cast<const f16x8*>(&As[(wm + i * 16 + (lane & 15)) * 64 + ko]);
        bfr[i] = *reinterpret_cast<const f16x8*>(&Bs[(wn + i * 16 + (lane & 15)) * 64 + ko]);
      }
      #pragma unroll
      for (int mi = 0; mi < 4; ++mi)
        #pragma unroll
        for (int ni = 0; ni < 4; ++ni)
          acc[mi][ni] = __builtin_amdgcn_mfma_f32_16x16x32_f16(af[mi], bfr[ni], acc[mi][ni], 0, 0, 0);
    }
    __syncthreads();
  }
  const int rb = (lane >> 4) * 4;
  const int cb = lane & 15;
  if (MODE == 0) {
    f16* tile = As;                      // 32KB alias (As+Bs contiguous)
    #pragma unroll
    for (int mi = 0; mi < 4; ++mi)
      #pragma unroll
      for (int ni = 0; ni < 4; ++ni) {
        const int col = wn + ni * 16 + cb;
        const float bv = bias[n0 + col];
        #pragma unroll
        for (int r = 0; r < 4; ++r)
          tile[(wm + mi * 16 + rb + r) * 128 + col] = (f16)tanhf(acc[mi][ni][r] + bv);
      }
    __syncthreads();
    f16* H2 = (f16*)Cout;
    const int row = tid >> 1;
    const int c0  = (tid & 1) * 64;
    #pragma unroll
    for (int i = 0; i < 16; ++i) {
      union { f16x4 v; unsigned long long u; } cv;
      cv.v = *reinterpret_cast<const f16x4*>(&tile[row * 128 + c0 + i * 4]);
      __hip_atomic_store(reinterpret_cast<unsigned long long*>(
          &H2[(size_t)(m0 + row) * kH + n0 + c0 + i * 4]),
          cv.u, __ATOMIC_RELAXED, __HIP_MEMORY_SCOPE_AGENT);
    }
  } else {
    float* C = (float*)Cout;
    #pragma unroll
    for (int mi = 0; mi < 4; ++mi)
      #pragma unroll
      for (int ni = 0; ni < 4; ++ni) {
        const int col = n0 + wn + ni * 16 + cb;
        const float bv = bias[col];
        #pragma unroll
        for (int r = 0; r < 4; ++r)
          C[(size_t)(m0 + wm + mi * 16 + rb + r) * N + col] = acc[mi][ni][r] + bv;
      }
  }
}

// ---------------- gi GEMM (standalone, occupancy-hinted) ----------------

__global__ __launch_bounds__(256, 4)
void gemm_bt_kernel(const f16* __restrict__ A, const f16* __restrict__ Bt,
                    const float* __restrict__ bias, float* __restrict__ C,
                    int M, int N, int K) {
  __shared__ __align__(16) f16 sb[2 * 128 * 64];
  tile_gemm<1>(sb, sb + 8192, A + (size_t)(blockIdx.x * 128) * K,
               Bt + (size_t)(blockIdx.y * 128) * K, bias, C, N, K,
               blockIdx.x * 128, blockIdx.y * 128);
}

// ---------------- merged concat -> out kernel ----------------
// Grid 1024 = 256 CU x 4 blocks (LB 256,4): ALL blocks resident by capacity ->
// static schedule is deadlock-free (concat items [0..127] wait on nothing;
// out items wait only on conc[r], produced by resident blocks).

__global__ __launch_bounds__(256, 4)
void concat_out_kernel(const f16* __restrict__ CAT, const f16* __restrict__ cWh,
                       const float* __restrict__ cb, f16* __restrict__ H2,
                       const f16* __restrict__ oWh, const float* __restrict__ ob,
                       float* __restrict__ outC, unsigned int* __restrict__ ctr) {
  __shared__ __align__(16) f16 sb[2 * 128 * 64];
  f16* As = sb;
  f16* Bs = sb + 8192;
  const int tid = threadIdx.x;
  for (int item = blockIdx.x; item < 4128; item += 1024) {
    if (item < 128) {
      const int r  = item & 15;
      const int ct = item >> 4;
      tile_gemm<0>(As, Bs, CAT + (size_t)(128 * r) * k3H, cWh + (size_t)(128 * ct) * k3H,
                   cb, H2, kH, k3H, 128 * r, 128 * ct);
      __syncthreads();   // drain write-through H2 stores (vmcnt(0) before barrier)
      if (tid == 0)
        __hip_atomic_fetch_add(&ctr[C_CONC + 32 * r], 1u,
                               __ATOMIC_RELAXED, __HIP_MEMORY_SCOPE_SYSTEM);
    } else {
      const int j  = item - 128;
      const int r  = j & 15;
      const int ct = j >> 4;
      if (tid == 0) {
        while (__hip_atomic_load(&ctr[C_CONC + 32 * r], __ATOMIC_RELAXED,
                                 __HIP_MEMORY_SCOPE_SYSTEM) < 8u)
          __builtin_amdgcn_s_sleep(16);
      }
      __syncthreads();
      __builtin_amdgcn_fence(__ATOMIC_ACQUIRE, "agent");
      tile_gemm<1>(As, Bs, H2 + (size_t)(128 * r) * kH, oWh + (size_t)(128 * ct) * kH,
                   ob, outC, kV, kH, 128 * r, 128 * ct);
    }
    __syncthreads();     // LDS reuse across items
  }
}

// ---------------- MEGA (R5-proven): gru (0..63) | attn (64..191) | cvt (192..511) ------

constexpr int kGruBlks = 64;
constexpr int kAttnBlks = 128;
constexpr int kCvtBlks = 320;
constexpr int kMegaBlks = kGruBlks + kAttnBlks + kCvtBlks;

__global__ __launch_bounds__(256, 1)
void mega_kernel(const f16* __restrict__ Whh, const float* __restrict__ bhh,
                 const float* __restrict__ gi, const float* __restrict__ lh,
                 f16* __restrict__ HHa, f16* __restrict__ HHb,
                 f16* __restrict__ cath, float* __restrict__ hiddenOut,
                 unsigned int* __restrict__ flags,
                 const float* __restrict__ enc0, const float* __restrict__ enc1,
                 const float* __restrict__ u2, const float* __restrict__ biasS,
                 float* __restrict__ uw, float* __restrict__ bw,
                 const float* __restrict__ oW, f16* __restrict__ oWh,
                 const float* __restrict__ cW, f16* __restrict__ cWh) {
  __shared__ union SM {
    float ghp[4][64][52];
    struct { float4 u2s[256]; float srow[kT]; float red[8]; } at;
  } sm;
  const int bid = blockIdx.x;
  const int tid = threadIdx.x;
  const int wave = tid >> 6;
  const int lane = tid & 63;

  if (bid < kGruBlks) {
    // ================= GRU role (unchanged R5 protocol) =================
    const int ln   = lane & 15;
    const int khi  = lane >> 4;
    const int j0   = bid * 16;
    const int kw   = wave * 256;
    const int fm   = tid >> 2;
    const int fc   = (tid & 3) * 4;
    const int myprod = wave * 16 + ln;

    f16x8 bfr[3][8];
    #pragma unroll
    for (int s = 0; s < 3; ++s)
      #pragma unroll
      for (int ks = 0; ks < 8; ++ks)
        bfr[s][ks] = *reinterpret_cast<const f16x8*>(
            &Whh[(size_t)(s * kH + j0 + ln) * kH + kw + ks * 32 + khi * 8]);

    float hreg[4], bR[4], bZ[4], bN[4];
    #pragma unroll
    for (int e = 0; e < 4; ++e) {
      const int j = j0 + fc + e;
      hreg[e] = lh[(size_t)fm * kH + j];
      bR[e] = bhh[j]; bZ[e] = bhh[kH + j]; bN[e] = bhh[2 * kH + j];
    }

    for (int step = 0; step < kN; ++step) {
      const f16* hh  = (step & 1) ? HHb : HHa;
      f16*       hho = (step & 1) ? HHa : HHb;

      float4 giL[3];
      {
        const size_t mm = (size_t)step * kB + fm;
        #pragma unroll
        for (int s = 0; s < 3; ++s)
          giL[s] = *reinterpret_cast<const float4*>(&gi[mm * k3H + s * kH + j0 + fc]);
      }

      if (step > 0) {
        while (true) {
          unsigned int f = __hip_atomic_load(&flags[myprod], __ATOMIC_RELAXED,
                                             __HIP_MEMORY_SCOPE_SYSTEM);
          if (__all(f >= (unsigned int)step)) break;
          __builtin_amdgcn_s_sleep(1);
        }
        __builtin_amdgcn_fence(__ATOMIC_ACQUIRE, "agent");
      }

      f16x8 af[8][4];
      #pragma unroll
      for (int ks = 0; ks < 8; ++ks)
        #pragma unroll
        for (int mi = 0; mi < 4; ++mi)
          af[ks][mi] = *reinterpret_cast<const f16x8*>(
              &hh[(size_t)(mi * 16 + ln) * kH + kw + ks * 32 + khi * 8]);

      f32x4v acc[4][3] = {};
      #pragma unroll
      for (int ks = 0; ks < 8; ++ks)
        #pragma unroll
        for (int mi = 0; mi < 4; ++mi)
          #pragma unroll
          for (int s = 0; s < 3; ++s)
            acc[mi][s] = __builtin_amdgcn_mfma_f32_16x16x32_f16(af[ks][mi], bfr[s][ks], acc[mi][s], 0, 0, 0);

      #pragma unroll
      for (int mi = 0; mi < 4; ++mi)
        #pragma unroll
        for (int s = 0; s < 3; ++s)
          #pragma unroll
          for (int r = 0; r < 4; ++r)
            sm.ghp[wave][mi * 16 + khi * 4 + r][s * 16 + ln] = acc[mi][s][r];
      __syncthreads();

      float4 gr4 = {0,0,0,0}, gz4 = {0,0,0,0}, gn4 = {0,0,0,0};
      #pragma unroll
      for (int w = 0; w < 4; ++w) {
        float4 a = *reinterpret_cast<const float4*>(&sm.ghp[w][fm][fc]);
        float4 b = *reinterpret_cast<const float4*>(&sm.ghp[w][fm][16 + fc]);
        float4 c = *reinterpret_cast<const float4*>(&sm.ghp[w][fm][32 + fc]);
        gr4.x += a.x; gr4.y += a.y; gr4.z += a.z; gr4.w += a.w;
        gz4.x += b.x; gz4.y += b.y; gz4.z += b.z; gz4.w += b.w;
        gn4.x += c.x; gn4.y += c.y; gn4.z += c.z; gn4.w += c.w;
      }
      float hv[4];
      const float* grp = &gr4.x; const float* gzp = &gz4.x; const float* gnp = &gn4.x;
      const float* g0 = &giL[0].x; const float* g1 = &giL[1].x; const float* g2 = &giL[2].x;
      #pragma unroll
      for (int e = 0; e < 4; ++e) {
        const float r  = 1.0f / (1.0f + expf(-(g0[e] + grp[e] + bR[e])));
        const float z  = 1.0f / (1.0f + expf(-(g1[e] + gzp[e] + bZ[e])));
        const float nn = tanhf(g2[e] + r * (gnp[e] + bN[e]));
        hv[e] = (1.0f - z) * nn + z * hreg[e];
        hreg[e] = hv[e];
      }
      const uint32_t p01 = pack_f16x2((f16)hv[0], (f16)hv[1]);
      const uint32_t p23 = pack_f16x2((f16)hv[2], (f16)hv[3]);
      const unsigned long long pk64 = (unsigned long long)p01 | ((unsigned long long)p23 << 32);
      __hip_atomic_store(reinterpret_cast<unsigned long long*>(&hho[(size_t)fm * kH + j0 + fc]),
                         pk64, __ATOMIC_RELAXED, __HIP_MEMORY_SCOPE_AGENT);
      __syncthreads();   // drains vmcnt -> hho at coherence point; guards ghp
      if (step < kN - 1 && tid == 0)
        __hip_atomic_store(&flags[bid], (unsigned int)(step + 1),
                           __ATOMIC_RELAXED, __HIP_MEMORY_SCOPE_SYSTEM);
      // non-gating stores after flag publish (cross-dispatch visibility via kernel-end release)
      uint2 pku; pku.x = p01; pku.y = p23;
      *reinterpret_cast<uint2*>(&cath[((size_t)step * kB + fm) * k3H + j0 + fc]) = pku;
      if (step == kN - 1) {
        float4 hv4 = { hv[0], hv[1], hv[2], hv[3] };
        *reinterpret_cast<float4*>(&hiddenOut[(size_t)fm * kH + j0 + fc]) = hv4;
      }
    }
  } else if (bid < kGruBlks + kAttnBlks) {
    // ================= attention role =================
    const int idx = bid - kGruBlks;
    const int e = idx >> 6, b = idx & 63;
    const float* enc = e ? enc1 : enc0;

    sm.at.u2s[tid] = *reinterpret_cast<const float4*>(&u2[tid * 4]);
    __syncthreads();
    const float bias = biasS[0];

    for (int t = wave; t < kT; t += 4) {
      const float* row = enc + ((size_t)t * kB + b) * kH + lane * 16;
      float s = 0.0f;
      #pragma unroll
      for (int i = 0; i < 4; ++i) {
        float4 ev = reinterpret_cast<const float4*>(row)[i];
        float4 uv = sm.at.u2s[lane * 4 + i];
        s += ev.x * uv.x + ev.y * uv.y + ev.z * uv.z + ev.w * uv.w;
      }
      #pragma unroll
      for (int o = 32; o > 0; o >>= 1) s += __shfl_xor(s, o);
      if (lane == 0) sm.at.srow[t] = s + bias;
    }
    __syncthreads();

    float lmax = -1e30f;
    for (int t = tid; t < kT; t += 256) lmax = fmaxf(lmax, sm.at.srow[t]);
    #pragma unroll
    for (int o = 32; o > 0; o >>= 1) lmax = fmaxf(lmax, __shfl_xor(lmax, o));
    if (lane == 0) sm.at.red[wave] = lmax;
    __syncthreads();
    const float m = fmaxf(fmaxf(sm.at.red[0], sm.at.red[1]), fmaxf(sm.at.red[2], sm.at.red[3]));
    float lsum = 0.0f;
    for (int t = tid; t < kT; t += 256) {
      float ev = expf(sm.at.srow[t] - m);
      sm.at.srow[t] = ev;
      lsum += ev;
    }
    #pragma unroll
    for (int o = 32; o > 0; o >>= 1) lsum += __shfl_xor(lsum, o);
    if (lane == 0) sm.at.red[4 + wave] = lsum;
    __syncthreads();
    const float inv = 1.0f / (sm.at.red[4] + sm.at.red[5] + sm.at.red[6] + sm.at.red[7]);
    for (int t = tid; t < kT; t += 256) sm.at.srow[t] *= inv;
    __syncthreads();

    float* outp = (e ? bw : uw) + (size_t)b * kN * kT;
    for (int n = 0; n < kN; ++n)
      for (int t = tid; t < kT; t += 256)
        __builtin_nontemporal_store(sm.at.srow[t], &outp[n * kT + t]);

    const int j = tid * 4;
    float4 acc = {0,0,0,0};
    for (int t = 0; t < kT; ++t) {
      const float wt = sm.at.srow[t];
      const float4 ev = *reinterpret_cast<const float4*>(&enc[((size_t)t * kB + b) * kH + j]);
      acc.x += wt * ev.x; acc.y += wt * ev.y; acc.z += wt * ev.z; acc.w += wt * ev.w;
    }
    f16x4 cv = { (f16)acc.x, (f16)acc.y, (f16)acc.z, (f16)acc.w };
    #pragma unroll
    for (int n = 0; n < kN; ++n)
      *reinterpret_cast<f16x4*>(&cath[((size_t)(n * kB + b)) * k3H + kH + e * kH + j]) = cv;
  } else {
    // ================= cvt role: oW then cW =================
    constexpr int nOW = kV * kH / 4;
    constexpr int nCW = kH * k3H / 4;
    const int stride = kCvtBlks * 256;
    for (int i = (bid - kGruBlks - kAttnBlks) * 256 + tid; i < nOW + nCW; i += stride) {
      if (i < nOW) {
        float4 v = reinterpret_cast<const float4*>(oW)[i];
        f16x4 o = { (f16)v.x, (f16)v.y, (f16)v.z, (f16)v.w };
        reinterpret_cast<f16x4*>(oWh)[i] = o;
      } else {
        const int k = i - nOW;
        float4 v = reinterpret_cast<const float4*>(cW)[k];
        f16x4 o = { (f16)v.x, (f16)v.y, (f16)v.z, (f16)v.w };
        reinterpret_cast<f16x4*>(cWh)[k] = o;
      }
    }
  }
}

}  // namespace

// ---------------- launch ----------------

extern "C" void kernel_launch(void* const* d_in, const int* in_sizes, int n_in,
                              void* d_out, int out_size, void* d_ws, size_t ws_size,
                              hipStream_t stream) {
  (void)in_sizes; (void)n_in; (void)out_size; (void)ws_size;
  const int*   seq    = (const int*)d_in[0];
  const float* lh     = (const float*)d_in[1];
  const float* enc0   = (const float*)d_in[2];
  const float* enc1   = (const float*)d_in[3];
  const float* emb    = (const float*)d_in[4];
  const float* W_ih   = (const float*)d_in[5];
  const float* W_hh   = (const float*)d_in[6];
  const float* b_ih   = (const float*)d_in[7];
  const float* b_hh   = (const float*)d_in[8];
  const float* attn_W = (const float*)d_in[9];
  const float* attn_b = (const float*)d_in[10];
  const float* attn_v = (const float*)d_in[11];
  const float* cW     = (const float*)d_in[12];
  const float* cb     = (const float*)d_in[13];
  const float* oW     = (const float*)d_in[14];
  const float* ob     = (const float*)d_in[15];
  float* out = (float*)d_out;

  char* ws = (char*)d_ws;
  constexpr size_t oWih = 0;                         // 3072x1024 f16
  constexpr size_t oWhh = oWih + 6291456;
  constexpr size_t oCW  = oWhh + 6291456;
  constexpr size_t oOW  = oCW + 6291456;             // 32000x1024 f16
  constexpr size_t oX   = oOW + 65536000;            // 2048x1024 f16
  constexpr size_t oGI  = oX + 4194304;              // 2048x3072 f32
  constexpr size_t oHH0 = oGI + 25165824;            // 64x1024 f16
  constexpr size_t oHH1 = oHH0 + 131072;
  constexpr size_t oCAT = oHH1 + 131072;             // 2048x3072 f16
  constexpr size_t oH2  = oCAT + 12582912;           // 2048x1024 f16
  constexpr size_t oCTR = oH2 + 4194304;             // counters + u2/biasS (8KB)

  f16*   Wih_h = (f16*)(ws + oWih);
  f16*   Whh_h = (f16*)(ws + oWhh);
  f16*   cW_h  = (f16*)(ws + oCW);
  f16*   oW_h  = (f16*)(ws + oOW);
  f16*   X_h   = (f16*)(ws + oX);
  float* GI    = (float*)(ws + oGI);
  f16*   HH0   = (f16*)(ws + oHH0);
  f16*   HH1   = (f16*)(ws + oHH1);
  f16*   CAT   = (f16*)(ws + oCAT);
  f16*   H2    = (f16*)(ws + oH2);
  unsigned int* CTR = (unsigned int*)(ws + oCTR);
  float* U2    = (float*)(CTR + C_U2);
  float* BS    = (float*)(CTR + C_BS);

  constexpr size_t oHidden = (size_t)kM * kV;        // 65,536,000
  constexpr size_t oUW = oHidden + (size_t)kB * kH;
  constexpr size_t oBW = oUW + (size_t)kB * kN * kT;

  // counter/u2 reset, then fused pre-pass (atomicAdds into zeroed CTR page)
  (void)hipMemsetAsync(CTR, 0, 8192, stream);
  pre_kernel<<<709, 256, 0, stream>>>(W_ih, Wih_h, W_hh, Whh_h, seq, emb, X_h,
                                      lh, HH0, attn_W, attn_b, attn_v, CTR);

  // gi = x @ W_ih^T + b_ih
  gemm_bt_kernel<<<dim3(16, 24), 256, 0, stream>>>(X_h, Wih_h, b_ih, GI, kM, k3H, kH);

  // MEGA: gru recurrence || attention || oW/cW converts   (R5-proven)
  mega_kernel<<<kMegaBlks, 256, 0, stream>>>(Whh_h, b_hh, GI, lh, HH0, HH1, CAT,
                                             out + oHidden, CTR,
                                             enc0, enc1, U2, BS,
                                             out + oUW, out + oBW,
                                             oW, oW_h, cW, cW_h);

  // concat -> out, merged with per-row readiness (all-resident grid 1024)
  concat_out_kernel<<<1024, 256, 0, stream>>>(CAT, cW_h, cb, H2, oW_h, ob, out, CTR);
}

// Round 14
// 636.877 us; speedup vs baseline: 1.1037x; 1.1037x over previous
//
#include <hip/hip_runtime.h>
#include <cstdint>
#include <cstddef>

namespace {

constexpr int kH  = 1024;
constexpr int kB  = 64;
constexpr int kN  = 32;
constexpr int kT  = 400;
constexpr int kV  = 32000;
constexpr int kM  = kN * kB;   // 2048
constexpr int k3H = 3 * kH;    // 3072

typedef _Float16 f16;
typedef _Float16 f16x4 __attribute__((ext_vector_type(4)));
typedef _Float16 f16x8 __attribute__((ext_vector_type(8)));
typedef float    f32x4v __attribute__((ext_vector_type(4)));

__device__ __forceinline__ void gload_lds16(const void* g, void* l) {
  __builtin_amdgcn_global_load_lds((__attribute__((address_space(1))) void*)g,
                                   (__attribute__((address_space(3))) void*)l,
                                   16, 0, 0);
}

__device__ __forceinline__ uint32_t pack_f16x2(f16 lo, f16 hi) {
  union { f16 h[2]; uint32_t u; } c;
  c.h[0] = lo; c.h[1] = hi;
  return c.u;
}

// CTR page layout (u32 words; memset 8192B before pre_kernel):
//   [0..63]     gru per-block step flags
//   [640..1663] u2 accumulator (1024 f32, atomicAdd by pre)
//   [1664]      biasS accumulator (f32)
constexpr int C_FLAGS = 0;
constexpr int C_U2    = 640;
constexpr int C_BS    = 1664;

// ---------------- fused pre-kernel: cvt Wih/Whh | gather | init | attn_prep ----------------

__global__ __launch_bounds__(256)
void pre_kernel(const float* __restrict__ Wih, f16* __restrict__ WihH,
                const float* __restrict__ Whh, f16* __restrict__ WhhH,
                const int* __restrict__ seq, const float* __restrict__ emb,
                f16* __restrict__ Xh, const float* __restrict__ lh,
                f16* __restrict__ HH0,
                const float* __restrict__ attnW, const float* __restrict__ attnB,
                const float* __restrict__ attnV, unsigned int* __restrict__ ctr) {
  const int bid = blockIdx.x, tid = threadIdx.x;
  if (bid < 512) {
    const float* src = (bid < 256) ? Wih : Whh;
    f16* dst = (bid < 256) ? WihH : WhhH;
    constexpr int n4 = k3H * kH / 4;
    for (int i = (bid & 255) * 256 + tid; i < n4; i += 256 * 256) {
      float4 v = reinterpret_cast<const float4*>(src)[i];
      f16x4 o = { (f16)v.x, (f16)v.y, (f16)v.z, (f16)v.w };
      reinterpret_cast<f16x4*>(dst)[i] = o;
    }
  } else if (bid < 640) {
    const int m0 = (bid - 512) * 16;
    for (int k = 0; k < 16; ++k) {
      const int m = m0 + k;
      const int tok = seq[m];
      float4 v = reinterpret_cast<const float4*>(emb + (size_t)tok * kH)[tid];
      f16x4 o = { (f16)v.x, (f16)v.y, (f16)v.z, (f16)v.w };
      reinterpret_cast<f16x4*>(Xh + (size_t)m * kH)[tid] = o;
    }
  } else if (bid < 644) {
    for (int i = (bid - 640) * 256 + tid; i < 16384; i += 1024) {
      float4 v = reinterpret_cast<const float4*>(lh)[i];
      f16x4 o = { (f16)v.x, (f16)v.y, (f16)v.z, (f16)v.w };
      reinterpret_cast<f16x4*>(HH0)[i] = o;
    }
  } else if (bid < 708) {
    // attn u2: coalesced rows, 64 blocks = 4 h-tiles x 16 k-chunks, atomicAdd
    const int b  = bid - 644;
    const int hc = b & 3;
    const int kc = b >> 2;
    const int h  = hc * 256 + tid;
    float sum = 0.0f;
    for (int k = kc * 64; k < kc * 64 + 64; ++k)
      sum += attnW[(size_t)k * (2 * kH) + kH + h] * attnV[k];
    atomicAdd(reinterpret_cast<float*>(ctr + C_U2) + h, sum);
  } else {
    if (tid < 64) {
      float s = 0.0f;
      for (int k = tid; k < kH; k += 64) s += attnB[k] * attnV[k];
      #pragma unroll
      for (int o = 32; o > 0; o >>= 1) s += __shfl_xor(s, o);
      if (tid == 0) atomicAdd(reinterpret_cast<float*>(ctr + C_BS), s);
    }
  }
}

// ---------------- proven 128x128 GEMM: C = A * Bt^T (+bias)(+tanh) ----------------
// __launch_bounds__(256, 4): 4 blocks/CU -- the R12-verified occupancy lever
// (R1 profile: OccupancyPercent 30.8 with VGPR=80/LDS=32KB, neither capped).

template <bool TANH, typename OUT_T>
__global__ __launch_bounds__(256, 4)
void gemm_bt_kernel(const f16* __restrict__ A, const f16* __restrict__ Bt,
                    const float* __restrict__ bias, OUT_T* __restrict__ C,
                    int M, int N, int K) {
  __shared__ __align__(16) f16 As[128 * 64];
  __shared__ __align__(16) f16 Bs[128 * 64];
  const int tid  = threadIdx.x;
  const int wave = tid >> 6;
  const int lane = tid & 63;
  const int m0 = blockIdx.x * 128;
  const int n0 = blockIdx.y * 128;
  const int wm = (wave >> 1) * 64;
  const int wn = (wave & 1) * 64;
  const int rsub = lane >> 3;
  const int coff = (lane & 7) * 8;
  f32x4v acc[4][4] = {};
  const int nk = K >> 6;
  for (int kc = 0; kc < nk; ++kc) {
    const f16* Ag = A + (size_t)m0 * K + kc * 64;
    const f16* Bg = Bt + (size_t)n0 * K + kc * 64;
    for (int c = wave; c < 16; c += 4) {
      const int row = c * 8 + rsub;
      gload_lds16(Ag + (size_t)row * K + coff, &As[c * 512]);
      gload_lds16(Bg + (size_t)row * K + coff, &Bs[c * 512]);
    }
    __syncthreads();
    #pragma unroll
    for (int kk = 0; kk < 2; ++kk) {
      const int ko = kk * 32 + (lane >> 4) * 8;
      f16x8 af[4], bfr[4];
      #pragma unroll
      for (int i = 0; i < 4; ++i) {
        af[i]  = *reinterpret_cast<const f16x8*>(&As[(wm + i * 16 + (lane & 15)) * 64 + ko]);
        bfr[i] = *reinterpret_cast<const f16x8*>(&Bs[(wn + i * 16 + (lane & 15)) * 64 + ko]);
      }
      #pragma unroll
      for (int mi = 0; mi < 4; ++mi)
        #pragma unroll
        for (int ni = 0; ni < 4; ++ni)
          acc[mi][ni] = __builtin_amdgcn_mfma_f32_16x16x32_f16(af[mi], bfr[ni], acc[mi][ni], 0, 0, 0);
    }
    __syncthreads();
  }
  const int rb = (lane >> 4) * 4;
  const int cb = lane & 15;
  #pragma unroll
  for (int mi = 0; mi < 4; ++mi) {
    #pragma unroll
    for (int ni = 0; ni < 4; ++ni) {
      const int col = n0 + wn + ni * 16 + cb;
      const float bv = bias[col];
      #pragma unroll
      for (int r = 0; r < 4; ++r) {
        const int row = m0 + wm + mi * 16 + rb + r;
        float v = acc[mi][ni][r] + bv;
        if (TANH) v = tanhf(v);
        C[(size_t)row * N + col] = (OUT_T)v;
      }
    }
  }
}

// ---------------- MEGA (R5-proven): gru (0..63) | attn (64..191) | cvt (192..511) ------

constexpr int kGruBlks = 64;
constexpr int kAttnBlks = 128;
constexpr int kCvtBlks = 320;
constexpr int kMegaBlks = kGruBlks + kAttnBlks + kCvtBlks;

__global__ __launch_bounds__(256, 1)
void mega_kernel(const f16* __restrict__ Whh, const float* __restrict__ bhh,
                 const float* __restrict__ gi, const float* __restrict__ lh,
                 f16* __restrict__ HHa, f16* __restrict__ HHb,
                 f16* __restrict__ cath, float* __restrict__ hiddenOut,
                 unsigned int* __restrict__ flags,
                 const float* __restrict__ enc0, const float* __restrict__ enc1,
                 const float* __restrict__ u2, const float* __restrict__ biasS,
                 float* __restrict__ uw, float* __restrict__ bw,
                 const float* __restrict__ oW, f16* __restrict__ oWh,
                 const float* __restrict__ cW, f16* __restrict__ cWh) {
  __shared__ union SM {
    float ghp[4][64][52];
    struct { float4 u2s[256]; float srow[kT]; float red[8]; } at;
  } sm;
  const int bid = blockIdx.x;
  const int tid = threadIdx.x;
  const int wave = tid >> 6;
  const int lane = tid & 63;

  if (bid < kGruBlks) {
    // ================= GRU role (unchanged R5 protocol) =================
    const int ln   = lane & 15;
    const int khi  = lane >> 4;
    const int j0   = bid * 16;
    const int kw   = wave * 256;
    const int fm   = tid >> 2;
    const int fc   = (tid & 3) * 4;
    const int myprod = wave * 16 + ln;

    f16x8 bfr[3][8];
    #pragma unroll
    for (int s = 0; s < 3; ++s)
      #pragma unroll
      for (int ks = 0; ks < 8; ++ks)
        bfr[s][ks] = *reinterpret_cast<const f16x8*>(
            &Whh[(size_t)(s * kH + j0 + ln) * kH + kw + ks * 32 + khi * 8]);

    float hreg[4], bR[4], bZ[4], bN[4];
    #pragma unroll
    for (int e = 0; e < 4; ++e) {
      const int j = j0 + fc + e;
      hreg[e] = lh[(size_t)fm * kH + j];
      bR[e] = bhh[j]; bZ[e] = bhh[kH + j]; bN[e] = bhh[2 * kH + j];
    }

    for (int step = 0; step < kN; ++step) {
      const f16* hh  = (step & 1) ? HHb : HHa;
      f16*       hho = (step & 1) ? HHa : HHb;

      float4 giL[3];
      {
        const size_t mm = (size_t)step * kB + fm;
        #pragma unroll
        for (int s = 0; s < 3; ++s)
          giL[s] = *reinterpret_cast<const float4*>(&gi[mm * k3H + s * kH + j0 + fc]);
      }

      if (step > 0) {
        while (true) {
          unsigned int f = __hip_atomic_load(&flags[myprod], __ATOMIC_RELAXED,
                                             __HIP_MEMORY_SCOPE_SYSTEM);
          if (__all(f >= (unsigned int)step)) break;
          __builtin_amdgcn_s_sleep(1);
        }
        __builtin_amdgcn_fence(__ATOMIC_ACQUIRE, "agent");
      }

      f16x8 af[8][4];
      #pragma unroll
      for (int ks = 0; ks < 8; ++ks)
        #pragma unroll
        for (int mi = 0; mi < 4; ++mi)
          af[ks][mi] = *reinterpret_cast<const f16x8*>(
              &hh[(size_t)(mi * 16 + ln) * kH + kw + ks * 32 + khi * 8]);

      f32x4v acc[4][3] = {};
      #pragma unroll
      for (int ks = 0; ks < 8; ++ks)
        #pragma unroll
        for (int mi = 0; mi < 4; ++mi)
          #pragma unroll
          for (int s = 0; s < 3; ++s)
            acc[mi][s] = __builtin_amdgcn_mfma_f32_16x16x32_f16(af[ks][mi], bfr[s][ks], acc[mi][s], 0, 0, 0);

      #pragma unroll
      for (int mi = 0; mi < 4; ++mi)
        #pragma unroll
        for (int s = 0; s < 3; ++s)
          #pragma unroll
          for (int r = 0; r < 4; ++r)
            sm.ghp[wave][mi * 16 + khi * 4 + r][s * 16 + ln] = acc[mi][s][r];
      __syncthreads();

      float4 gr4 = {0,0,0,0}, gz4 = {0,0,0,0}, gn4 = {0,0,0,0};
      #pragma unroll
      for (int w = 0; w < 4; ++w) {
        float4 a = *reinterpret_cast<const float4*>(&sm.ghp[w][fm][fc]);
        float4 b = *reinterpret_cast<const float4*>(&sm.ghp[w][fm][16 + fc]);
        float4 c = *reinterpret_cast<const float4*>(&sm.ghp[w][fm][32 + fc]);
        gr4.x += a.x; gr4.y += a.y; gr4.z += a.z; gr4.w += a.w;
        gz4.x += b.x; gz4.y += b.y; gz4.z += b.z; gz4.w += b.w;
        gn4.x += c.x; gn4.y += c.y; gn4.z += c.z; gn4.w += c.w;
      }
      float hv[4];
      const float* grp = &gr4.x; const float* gzp = &gz4.x; const float* gnp = &gn4.x;
      const float* g0 = &giL[0].x; const float* g1 = &giL[1].x; const float* g2 = &giL[2].x;
      #pragma unroll
      for (int e = 0; e < 4; ++e) {
        const float r  = 1.0f / (1.0f + expf(-(g0[e] + grp[e] + bR[e])));
        const float z  = 1.0f / (1.0f + expf(-(g1[e] + gzp[e] + bZ[e])));
        const float nn = tanhf(g2[e] + r * (gnp[e] + bN[e]));
        hv[e] = (1.0f - z) * nn + z * hreg[e];
        hreg[e] = hv[e];
      }
      const uint32_t p01 = pack_f16x2((f16)hv[0], (f16)hv[1]);
      const uint32_t p23 = pack_f16x2((f16)hv[2], (f16)hv[3]);
      const unsigned long long pk64 = (unsigned long long)p01 | ((unsigned long long)p23 << 32);
      __hip_atomic_store(reinterpret_cast<unsigned long long*>(&hho[(size_t)fm * kH + j0 + fc]),
                         pk64, __ATOMIC_RELAXED, __HIP_MEMORY_SCOPE_AGENT);
      __syncthreads();   // drains vmcnt -> hho at coherence point; guards ghp
      if (step < kN - 1 && tid == 0)
        __hip_atomic_store(&flags[bid], (unsigned int)(step + 1),
                           __ATOMIC_RELAXED, __HIP_MEMORY_SCOPE_SYSTEM);
      // non-gating stores after flag publish (cross-dispatch visibility via kernel-end release)
      uint2 pku; pku.x = p01; pku.y = p23;
      *reinterpret_cast<uint2*>(&cath[((size_t)step * kB + fm) * k3H + j0 + fc]) = pku;
      if (step == kN - 1) {
        float4 hv4 = { hv[0], hv[1], hv[2], hv[3] };
        *reinterpret_cast<float4*>(&hiddenOut[(size_t)fm * kH + j0 + fc]) = hv4;
      }
    }
  } else if (bid < kGruBlks + kAttnBlks) {
    // ================= attention role =================
    const int idx = bid - kGruBlks;
    const int e = idx >> 6, b = idx & 63;
    const float* enc = e ? enc1 : enc0;

    sm.at.u2s[tid] = *reinterpret_cast<const float4*>(&u2[tid * 4]);
    __syncthreads();
    const float bias = biasS[0];

    for (int t = wave; t < kT; t += 4) {
      const float* row = enc + ((size_t)t * kB + b) * kH + lane * 16;
      float s = 0.0f;
      #pragma unroll
      for (int i = 0; i < 4; ++i) {
        float4 ev = reinterpret_cast<const float4*>(row)[i];
        float4 uv = sm.at.u2s[lane * 4 + i];
        s += ev.x * uv.x + ev.y * uv.y + ev.z * uv.z + ev.w * uv.w;
      }
      #pragma unroll
      for (int o = 32; o > 0; o >>= 1) s += __shfl_xor(s, o);
      if (lane == 0) sm.at.srow[t] = s + bias;
    }
    __syncthreads();

    float lmax = -1e30f;
    for (int t = tid; t < kT; t += 256) lmax = fmaxf(lmax, sm.at.srow[t]);
    #pragma unroll
    for (int o = 32; o > 0; o >>= 1) lmax = fmaxf(lmax, __shfl_xor(lmax, o));
    if (lane == 0) sm.at.red[wave] = lmax;
    __syncthreads();
    const float m = fmaxf(fmaxf(sm.at.red[0], sm.at.red[1]), fmaxf(sm.at.red[2], sm.at.red[3]));
    float lsum = 0.0f;
    for (int t = tid; t < kT; t += 256) {
      float ev = expf(sm.at.srow[t] - m);
      sm.at.srow[t] = ev;
      lsum += ev;
    }
    #pragma unroll
    for (int o = 32; o > 0; o >>= 1) lsum += __shfl_xor(lsum, o);
    if (lane == 0) sm.at.red[4 + wave] = lsum;
    __syncthreads();
    const float inv = 1.0f / (sm.at.red[4] + sm.at.red[5] + sm.at.red[6] + sm.at.red[7]);
    for (int t = tid; t < kT; t += 256) sm.at.srow[t] *= inv;
    __syncthreads();

    float* outp = (e ? bw : uw) + (size_t)b * kN * kT;
    for (int n = 0; n < kN; ++n)
      for (int t = tid; t < kT; t += 256)
        __builtin_nontemporal_store(sm.at.srow[t], &outp[n * kT + t]);

    const int j = tid * 4;
    float4 acc = {0,0,0,0};
    for (int t = 0; t < kT; ++t) {
      const float wt = sm.at.srow[t];
      const float4 ev = *reinterpret_cast<const float4*>(&enc[((size_t)t * kB + b) * kH + j]);
      acc.x += wt * ev.x; acc.y += wt * ev.y; acc.z += wt * ev.z; acc.w += wt * ev.w;
    }
    f16x4 cv = { (f16)acc.x, (f16)acc.y, (f16)acc.z, (f16)acc.w };
    #pragma unroll
    for (int n = 0; n < kN; ++n)
      *reinterpret_cast<f16x4*>(&cath[((size_t)(n * kB + b)) * k3H + kH + e * kH + j]) = cv;
  } else {
    // ================= cvt role: oW then cW =================
    constexpr int nOW = kV * kH / 4;
    constexpr int nCW = kH * k3H / 4;
    const int stride = kCvtBlks * 256;
    for (int i = (bid - kGruBlks - kAttnBlks) * 256 + tid; i < nOW + nCW; i += stride) {
      if (i < nOW) {
        float4 v = reinterpret_cast<const float4*>(oW)[i];
        f16x4 o = { (f16)v.x, (f16)v.y, (f16)v.z, (f16)v.w };
        reinterpret_cast<f16x4*>(oWh)[i] = o;
      } else {
        const int k = i - nOW;
        float4 v = reinterpret_cast<const float4*>(cW)[k];
        f16x4 o = { (f16)v.x, (f16)v.y, (f16)v.z, (f16)v.w };
        reinterpret_cast<f16x4*>(cWh)[k] = o;
      }
    }
  }
}

}  // namespace

// ---------------- launch ----------------

extern "C" void kernel_launch(void* const* d_in, const int* in_sizes, int n_in,
                              void* d_out, int out_size, void* d_ws, size_t ws_size,
                              hipStream_t stream) {
  (void)in_sizes; (void)n_in; (void)out_size; (void)ws_size;
  const int*   seq    = (const int*)d_in[0];
  const float* lh     = (const float*)d_in[1];
  const float* enc0   = (const float*)d_in[2];
  const float* enc1   = (const float*)d_in[3];
  const float* emb    = (const float*)d_in[4];
  const float* W_ih   = (const float*)d_in[5];
  const float* W_hh   = (const float*)d_in[6];
  const float* b_ih   = (const float*)d_in[7];
  const float* b_hh   = (const float*)d_in[8];
  const float* attn_W = (const float*)d_in[9];
  const float* attn_b = (const float*)d_in[10];
  const float* attn_v = (const float*)d_in[11];
  const float* cW     = (const float*)d_in[12];
  const float* cb     = (const float*)d_in[13];
  const float* oW     = (const float*)d_in[14];
  const float* ob     = (const float*)d_in[15];
  float* out = (float*)d_out;

  char* ws = (char*)d_ws;
  constexpr size_t oWih = 0;                         // 3072x1024 f16
  constexpr size_t oWhh = oWih + 6291456;
  constexpr size_t oCW  = oWhh + 6291456;
  constexpr size_t oOW  = oCW + 6291456;             // 32000x1024 f16
  constexpr size_t oX   = oOW + 65536000;            // 2048x1024 f16
  constexpr size_t oGI  = oX + 4194304;              // 2048x3072 f32
  constexpr size_t oHH0 = oGI + 25165824;            // 64x1024 f16
  constexpr size_t oHH1 = oHH0 + 131072;
  constexpr size_t oCAT = oHH1 + 131072;             // 2048x3072 f16
  constexpr size_t oH2  = oCAT + 12582912;           // 2048x1024 f16
  constexpr size_t oCTR = oH2 + 4194304;             // counters + u2/biasS (8KB)

  f16*   Wih_h = (f16*)(ws + oWih);
  f16*   Whh_h = (f16*)(ws + oWhh);
  f16*   cW_h  = (f16*)(ws + oCW);
  f16*   oW_h  = (f16*)(ws + oOW);
  f16*   X_h   = (f16*)(ws + oX);
  float* GI    = (float*)(ws + oGI);
  f16*   HH0   = (f16*)(ws + oHH0);
  f16*   HH1   = (f16*)(ws + oHH1);
  f16*   CAT   = (f16*)(ws + oCAT);
  f16*   H2    = (f16*)(ws + oH2);
  unsigned int* CTR = (unsigned int*)(ws + oCTR);
  float* U2    = (float*)(CTR + C_U2);
  float* BS    = (float*)(CTR + C_BS);

  constexpr size_t oHidden = (size_t)kM * kV;        // 65,536,000
  constexpr size_t oUW = oHidden + (size_t)kB * kH;
  constexpr size_t oBW = oUW + (size_t)kB * kN * kT;

  // counter/u2 reset, then fused pre-pass (atomicAdds into zeroed CTR page)
  (void)hipMemsetAsync(CTR, 0, 8192, stream);
  pre_kernel<<<709, 256, 0, stream>>>(W_ih, Wih_h, W_hh, Whh_h, seq, emb, X_h,
                                      lh, HH0, attn_W, attn_b, attn_v, CTR);

  // gi = x @ W_ih^T + b_ih
  gemm_bt_kernel<false, float><<<dim3(16, 24), 256, 0, stream>>>(X_h, Wih_h, b_ih, GI, kM, k3H, kH);

  // MEGA: gru recurrence || attention || oW/cW converts   (R5-proven)
  mega_kernel<<<kMegaBlks, 256, 0, stream>>>(Whh_h, b_hh, GI, lh, HH0, HH1, CAT,
                                             out + oHidden, CTR,
                                             enc0, enc1, U2, BS,
                                             out + oUW, out + oBW,
                                             oW, oW_h, cW, cW_h);

  // h = tanh(cat @ concat_W^T + concat_b)
  gemm_bt_kernel<true, f16><<<dim3(16, 8), 256, 0, stream>>>(CAT, cW_h, cb, H2, kM, kH, k3H);
  // output = h @ out_W^T + out_b   (proven 128x128, occupancy hint 4 blocks/CU)
  gemm_bt_kernel<false, float><<<dim3(16, 250), 256, 0, stream>>>(H2, oW_h, ob, out, kM, kV, kH);
}

// Round 15
// 628.137 us; speedup vs baseline: 1.1191x; 1.0139x over previous
//
#include <hip/hip_runtime.h>
#include <cstdint>
#include <cstddef>

namespace {

constexpr int kH  = 1024;
constexpr int kB  = 64;
constexpr int kN  = 32;
constexpr int kT  = 400;
constexpr int kV  = 32000;
constexpr int kM  = kN * kB;   // 2048
constexpr int k3H = 3 * kH;    // 3072

typedef _Float16 f16;
typedef _Float16 f16x4 __attribute__((ext_vector_type(4)));
typedef _Float16 f16x8 __attribute__((ext_vector_type(8)));
typedef float    f32x4v __attribute__((ext_vector_type(4)));

__device__ __forceinline__ void gload_lds16(const void* g, void* l) {
  __builtin_amdgcn_global_load_lds((__attribute__((address_space(1))) void*)g,
                                   (__attribute__((address_space(3))) void*)l,
                                   16, 0, 0);
}

__device__ __forceinline__ uint32_t pack_f16x2(f16 lo, f16 hi) {
  union { f16 h[2]; uint32_t u; } c;
  c.h[0] = lo; c.h[1] = hi;
  return c.u;
}

// CTR page layout (u32 words; memset 16384B before pre_kernel):
//   [b*32], b<64   gru per-block step flags -- ONE 128B CACHE LINE EACH
//                  (R14 had all 64 flags in 2 lines -> hot-line serialization)
//   [2048..3071]   u2 accumulator (1024 f32, atomicAdd by pre)
//   [3072]         biasS accumulator (f32)
constexpr int C_FLAGSTRIDE = 32;
constexpr int C_U2 = 2048;
constexpr int C_BS = 3072;

// ---------------- fused pre-kernel: cvt Wih/Whh | gather | init | attn_prep ----------------

__global__ __launch_bounds__(256)
void pre_kernel(const float* __restrict__ Wih, f16* __restrict__ WihH,
                const float* __restrict__ Whh, f16* __restrict__ WhhH,
                const int* __restrict__ seq, const float* __restrict__ emb,
                f16* __restrict__ Xh, const float* __restrict__ lh,
                f16* __restrict__ HH0,
                const float* __restrict__ attnW, const float* __restrict__ attnB,
                const float* __restrict__ attnV, unsigned int* __restrict__ ctr) {
  const int bid = blockIdx.x, tid = threadIdx.x;
  if (bid < 512) {
    const float* src = (bid < 256) ? Wih : Whh;
    f16* dst = (bid < 256) ? WihH : WhhH;
    constexpr int n4 = k3H * kH / 4;
    for (int i = (bid & 255) * 256 + tid; i < n4; i += 256 * 256) {
      float4 v = reinterpret_cast<const float4*>(src)[i];
      f16x4 o = { (f16)v.x, (f16)v.y, (f16)v.z, (f16)v.w };
      reinterpret_cast<f16x4*>(dst)[i] = o;
    }
  } else if (bid < 640) {
    const int m0 = (bid - 512) * 16;
    for (int k = 0; k < 16; ++k) {
      const int m = m0 + k;
      const int tok = seq[m];
      float4 v = reinterpret_cast<const float4*>(emb + (size_t)tok * kH)[tid];
      f16x4 o = { (f16)v.x, (f16)v.y, (f16)v.z, (f16)v.w };
      reinterpret_cast<f16x4*>(Xh + (size_t)m * kH)[tid] = o;
    }
  } else if (bid < 644) {
    for (int i = (bid - 640) * 256 + tid; i < 16384; i += 1024) {
      float4 v = reinterpret_cast<const float4*>(lh)[i];
      f16x4 o = { (f16)v.x, (f16)v.y, (f16)v.z, (f16)v.w };
      reinterpret_cast<f16x4*>(HH0)[i] = o;
    }
  } else if (bid < 708) {
    // attn u2: coalesced rows, 64 blocks = 4 h-tiles x 16 k-chunks, atomicAdd
    const int b  = bid - 644;
    const int hc = b & 3;
    const int kc = b >> 2;
    const int h  = hc * 256 + tid;
    float sum = 0.0f;
    for (int k = kc * 64; k < kc * 64 + 64; ++k)
      sum += attnW[(size_t)k * (2 * kH) + kH + h] * attnV[k];
    atomicAdd(reinterpret_cast<float*>(ctr + C_U2) + h, sum);
  } else {
    if (tid < 64) {
      float s = 0.0f;
      for (int k = tid; k < kH; k += 64) s += attnB[k] * attnV[k];
      #pragma unroll
      for (int o = 32; o > 0; o >>= 1) s += __shfl_xor(s, o);
      if (tid == 0) atomicAdd(reinterpret_cast<float*>(ctr + C_BS), s);
    }
  }
}

// ---------------- proven 128x128 GEMM: C = A * Bt^T (+bias)(+tanh) ----------------

template <bool TANH, typename OUT_T>
__global__ __launch_bounds__(256, 4)
void gemm_bt_kernel(const f16* __restrict__ A, const f16* __restrict__ Bt,
                    const float* __restrict__ bias, OUT_T* __restrict__ C,
                    int M, int N, int K) {
  __shared__ __align__(16) f16 As[128 * 64];
  __shared__ __align__(16) f16 Bs[128 * 64];
  const int tid  = threadIdx.x;
  const int wave = tid >> 6;
  const int lane = tid & 63;
  const int m0 = blockIdx.x * 128;
  const int n0 = blockIdx.y * 128;
  const int wm = (wave >> 1) * 64;
  const int wn = (wave & 1) * 64;
  const int rsub = lane >> 3;
  const int coff = (lane & 7) * 8;
  f32x4v acc[4][4] = {};
  const int nk = K >> 6;
  for (int kc = 0; kc < nk; ++kc) {
    const f16* Ag = A + (size_t)m0 * K + kc * 64;
    const f16* Bg = Bt + (size_t)n0 * K + kc * 64;
    for (int c = wave; c < 16; c += 4) {
      const int row = c * 8 + rsub;
      gload_lds16(Ag + (size_t)row * K + coff, &As[c * 512]);
      gload_lds16(Bg + (size_t)row * K + coff, &Bs[c * 512]);
    }
    __syncthreads();
    #pragma unroll
    for (int kk = 0; kk < 2; ++kk) {
      const int ko = kk * 32 + (lane >> 4) * 8;
      f16x8 af[4], bfr[4];
      #pragma unroll
      for (int i = 0; i < 4; ++i) {
        af[i]  = *reinterpret_cast<const f16x8*>(&As[(wm + i * 16 + (lane & 15)) * 64 + ko]);
        bfr[i] = *reinterpret_cast<const f16x8*>(&Bs[(wn + i * 16 + (lane & 15)) * 64 + ko]);
      }
      #pragma unroll
      for (int mi = 0; mi < 4; ++mi)
        #pragma unroll
        for (int ni = 0; ni < 4; ++ni)
          acc[mi][ni] = __builtin_amdgcn_mfma_f32_16x16x32_f16(af[mi], bfr[ni], acc[mi][ni], 0, 0, 0);
    }
    __syncthreads();
  }
  const int rb = (lane >> 4) * 4;
  const int cb = lane & 15;
  #pragma unroll
  for (int mi = 0; mi < 4; ++mi) {
    #pragma unroll
    for (int ni = 0; ni < 4; ++ni) {
      const int col = n0 + wn + ni * 16 + cb;
      const float bv = bias[col];
      #pragma unroll
      for (int r = 0; r < 4; ++r) {
        const int row = m0 + wm + mi * 16 + rb + r;
        float v = acc[mi][ni][r] + bv;
        if (TANH) v = tanhf(v);
        C[(size_t)row * N + col] = (OUT_T)v;
      }
    }
  }
}

// ---------------- MEGA (R5-proven): gru (0..63) | attn (64..191) | cvt (192..511) ------

constexpr int kGruBlks = 64;
constexpr int kAttnBlks = 128;
constexpr int kCvtBlks = 320;
constexpr int kMegaBlks = kGruBlks + kAttnBlks + kCvtBlks;

__global__ __launch_bounds__(256, 1)
void mega_kernel(const f16* __restrict__ Whh, const float* __restrict__ bhh,
                 const float* __restrict__ gi, const float* __restrict__ lh,
                 f16* __restrict__ HHa, f16* __restrict__ HHb,
                 f16* __restrict__ cath, float* __restrict__ hiddenOut,
                 unsigned int* __restrict__ flags,
                 const float* __restrict__ enc0, const float* __restrict__ enc1,
                 const float* __restrict__ u2, const float* __restrict__ biasS,
                 float* __restrict__ uw, float* __restrict__ bw,
                 const float* __restrict__ oW, f16* __restrict__ oWh,
                 const float* __restrict__ cW, f16* __restrict__ cWh) {
  __shared__ union SM {
    float ghp[4][64][52];
    struct { float4 u2s[256]; float srow[kT]; float red[8]; } at;
  } sm;
  const int bid = blockIdx.x;
  const int tid = threadIdx.x;
  const int wave = tid >> 6;
  const int lane = tid & 63;

  if (bid < kGruBlks) {
    // ================= GRU role (R5 protocol; flags padded 1 line each) ==========
    const int ln   = lane & 15;
    const int khi  = lane >> 4;
    const int j0   = bid * 16;
    const int kw   = wave * 256;
    const int fm   = tid >> 2;
    const int fc   = (tid & 3) * 4;
    const int myprodw = (wave * 16 + ln) * C_FLAGSTRIDE;   // padded flag word

    f16x8 bfr[3][8];
    #pragma unroll
    for (int s = 0; s < 3; ++s)
      #pragma unroll
      for (int ks = 0; ks < 8; ++ks)
        bfr[s][ks] = *reinterpret_cast<const f16x8*>(
            &Whh[(size_t)(s * kH + j0 + ln) * kH + kw + ks * 32 + khi * 8]);

    float hreg[4], bR[4], bZ[4], bN[4];
    #pragma unroll
    for (int e = 0; e < 4; ++e) {
      const int j = j0 + fc + e;
      hreg[e] = lh[(size_t)fm * kH + j];
      bR[e] = bhh[j]; bZ[e] = bhh[kH + j]; bN[e] = bhh[2 * kH + j];
    }

    for (int step = 0; step < kN; ++step) {
      const f16* hh  = (step & 1) ? HHb : HHa;
      f16*       hho = (step & 1) ? HHa : HHb;

      float4 giL[3];
      {
        const size_t mm = (size_t)step * kB + fm;
        #pragma unroll
        for (int s = 0; s < 3; ++s)
          giL[s] = *reinterpret_cast<const float4*>(&gi[mm * k3H + s * kH + j0 + fc]);
      }

      if (step > 0) {
        while (true) {
          unsigned int f = __hip_atomic_load(&flags[myprodw], __ATOMIC_RELAXED,
                                             __HIP_MEMORY_SCOPE_SYSTEM);
          if (__all(f >= (unsigned int)step)) break;
          __builtin_amdgcn_s_sleep(1);
        }
        __builtin_amdgcn_fence(__ATOMIC_ACQUIRE, "agent");
      }

      f16x8 af[8][4];
      #pragma unroll
      for (int ks = 0; ks < 8; ++ks)
        #pragma unroll
        for (int mi = 0; mi < 4; ++mi)
          af[ks][mi] = *reinterpret_cast<const f16x8*>(
              &hh[(size_t)(mi * 16 + ln) * kH + kw + ks * 32 + khi * 8]);

      f32x4v acc[4][3] = {};
      #pragma unroll
      for (int ks = 0; ks < 8; ++ks)
        #pragma unroll
        for (int mi = 0; mi < 4; ++mi)
          #pragma unroll
          for (int s = 0; s < 3; ++s)
            acc[mi][s] = __builtin_amdgcn_mfma_f32_16x16x32_f16(af[ks][mi], bfr[s][ks], acc[mi][s], 0, 0, 0);

      #pragma unroll
      for (int mi = 0; mi < 4; ++mi)
        #pragma unroll
        for (int s = 0; s < 3; ++s)
          #pragma unroll
          for (int r = 0; r < 4; ++r)
            sm.ghp[wave][mi * 16 + khi * 4 + r][s * 16 + ln] = acc[mi][s][r];
      __syncthreads();

      float4 gr4 = {0,0,0,0}, gz4 = {0,0,0,0}, gn4 = {0,0,0,0};
      #pragma unroll
      for (int w = 0; w < 4; ++w) {
        float4 a = *reinterpret_cast<const float4*>(&sm.ghp[w][fm][fc]);
        float4 b = *reinterpret_cast<const float4*>(&sm.ghp[w][fm][16 + fc]);
        float4 c = *reinterpret_cast<const float4*>(&sm.ghp[w][fm][32 + fc]);
        gr4.x += a.x; gr4.y += a.y; gr4.z += a.z; gr4.w += a.w;
        gz4.x += b.x; gz4.y += b.y; gz4.z += b.z; gz4.w += b.w;
        gn4.x += c.x; gn4.y += c.y; gn4.z += c.z; gn4.w += c.w;
      }
      float hv[4];
      const float* grp = &gr4.x; const float* gzp = &gz4.x; const float* gnp = &gn4.x;
      const float* g0 = &giL[0].x; const float* g1 = &giL[1].x; const float* g2 = &giL[2].x;
      #pragma unroll
      for (int e = 0; e < 4; ++e) {
        const float r  = 1.0f / (1.0f + expf(-(g0[e] + grp[e] + bR[e])));
        const float z  = 1.0f / (1.0f + expf(-(g1[e] + gzp[e] + bZ[e])));
        const float nn = tanhf(g2[e] + r * (gnp[e] + bN[e]));
        hv[e] = (1.0f - z) * nn + z * hreg[e];
        hreg[e] = hv[e];
      }
      const uint32_t p01 = pack_f16x2((f16)hv[0], (f16)hv[1]);
      const uint32_t p23 = pack_f16x2((f16)hv[2], (f16)hv[3]);
      const unsigned long long pk64 = (unsigned long long)p01 | ((unsigned long long)p23 << 32);
      __hip_atomic_store(reinterpret_cast<unsigned long long*>(&hho[(size_t)fm * kH + j0 + fc]),
                         pk64, __ATOMIC_RELAXED, __HIP_MEMORY_SCOPE_AGENT);
      __syncthreads();   // drains vmcnt -> hho at coherence point; guards ghp
      if (step < kN - 1 && tid == 0)
        __hip_atomic_store(&flags[bid * C_FLAGSTRIDE], (unsigned int)(step + 1),
                           __ATOMIC_RELAXED, __HIP_MEMORY_SCOPE_SYSTEM);
      // non-gating stores after flag publish (cross-dispatch visibility via kernel-end release)
      uint2 pku; pku.x = p01; pku.y = p23;
      *reinterpret_cast<uint2*>(&cath[((size_t)step * kB + fm) * k3H + j0 + fc]) = pku;
      if (step == kN - 1) {
        float4 hv4 = { hv[0], hv[1], hv[2], hv[3] };
        *reinterpret_cast<float4*>(&hiddenOut[(size_t)fm * kH + j0 + fc]) = hv4;
      }
    }
  } else if (bid < kGruBlks + kAttnBlks) {
    // ================= attention role =================
    const int idx = bid - kGruBlks;
    const int e = idx >> 6, b = idx & 63;
    const float* enc = e ? enc1 : enc0;

    sm.at.u2s[tid] = *reinterpret_cast<const float4*>(&u2[tid * 4]);
    __syncthreads();
    const float bias = biasS[0];

    for (int t = wave; t < kT; t += 4) {
      const float* row = enc + ((size_t)t * kB + b) * kH + lane * 16;
      float s = 0.0f;
      #pragma unroll
      for (int i = 0; i < 4; ++i) {
        float4 ev = reinterpret_cast<const float4*>(row)[i];
        float4 uv = sm.at.u2s[lane * 4 + i];
        s += ev.x * uv.x + ev.y * uv.y + ev.z * uv.z + ev.w * uv.w;
      }
      #pragma unroll
      for (int o = 32; o > 0; o >>= 1) s += __shfl_xor(s, o);
      if (lane == 0) sm.at.srow[t] = s + bias;
    }
    __syncthreads();

    float lmax = -1e30f;
    for (int t = tid; t < kT; t += 256) lmax = fmaxf(lmax, sm.at.srow[t]);
    #pragma unroll
    for (int o = 32; o > 0; o >>= 1) lmax = fmaxf(lmax, __shfl_xor(lmax, o));
    if (lane == 0) sm.at.red[wave] = lmax;
    __syncthreads();
    const float m = fmaxf(fmaxf(sm.at.red[0], sm.at.red[1]), fmaxf(sm.at.red[2], sm.at.red[3]));
    float lsum = 0.0f;
    for (int t = tid; t < kT; t += 256) {
      float ev = expf(sm.at.srow[t] - m);
      sm.at.srow[t] = ev;
      lsum += ev;
    }
    #pragma unroll
    for (int o = 32; o > 0; o >>= 1) lsum += __shfl_xor(lsum, o);
    if (lane == 0) sm.at.red[4 + wave] = lsum;
    __syncthreads();
    const float inv = 1.0f / (sm.at.red[4] + sm.at.red[5] + sm.at.red[6] + sm.at.red[7]);
    for (int t = tid; t < kT; t += 256) sm.at.srow[t] *= inv;
    __syncthreads();

    float* outp = (e ? bw : uw) + (size_t)b * kN * kT;
    for (int n = 0; n < kN; ++n)
      for (int t = tid; t < kT; t += 256)
        __builtin_nontemporal_store(sm.at.srow[t], &outp[n * kT + t]);

    const int j = tid * 4;
    float4 acc = {0,0,0,0};
    for (int t = 0; t < kT; ++t) {
      const float wt = sm.at.srow[t];
      const float4 ev = *reinterpret_cast<const float4*>(&enc[((size_t)t * kB + b) * kH + j]);
      acc.x += wt * ev.x; acc.y += wt * ev.y; acc.z += wt * ev.z; acc.w += wt * ev.w;
    }
    f16x4 cv = { (f16)acc.x, (f16)acc.y, (f16)acc.z, (f16)acc.w };
    #pragma unroll
    for (int n = 0; n < kN; ++n)
      *reinterpret_cast<f16x4*>(&cath[((size_t)(n * kB + b)) * k3H + kH + e * kH + j]) = cv;
  } else {
    // ================= cvt role: oW then cW =================
    constexpr int nOW = kV * kH / 4;
    constexpr int nCW = kH * k3H / 4;
    const int stride = kCvtBlks * 256;
    for (int i = (bid - kGruBlks - kAttnBlks) * 256 + tid; i < nOW + nCW; i += stride) {
      if (i < nOW) {
        float4 v = reinterpret_cast<const float4*>(oW)[i];
        f16x4 o = { (f16)v.x, (f16)v.y, (f16)v.z, (f16)v.w };
        reinterpret_cast<f16x4*>(oWh)[i] = o;
      } else {
        const int k = i - nOW;
        float4 v = reinterpret_cast<const float4*>(cW)[k];
        f16x4 o = { (f16)v.x, (f16)v.y, (f16)v.z, (f16)v.w };
        reinterpret_cast<f16x4*>(cWh)[k] = o;
      }
    }
  }
}

}  // namespace

// ---------------- launch ----------------

extern "C" void kernel_launch(void* const* d_in, const int* in_sizes, int n_in,
                              void* d_out, int out_size, void* d_ws, size_t ws_size,
                              hipStream_t stream) {
  (void)in_sizes; (void)n_in; (void)out_size; (void)ws_size;
  const int*   seq    = (const int*)d_in[0];
  const float* lh     = (const float*)d_in[1];
  const float* enc0   = (const float*)d_in[2];
  const float* enc1   = (const float*)d_in[3];
  const float* emb    = (const float*)d_in[4];
  const float* W_ih   = (const float*)d_in[5];
  const float* W_hh   = (const float*)d_in[6];
  const float* b_ih   = (const float*)d_in[7];
  const float* b_hh   = (const float*)d_in[8];
  const float* attn_W = (const float*)d_in[9];
  const float* attn_b = (const float*)d_in[10];
  const float* attn_v = (const float*)d_in[11];
  const float* cW     = (const float*)d_in[12];
  const float* cb     = (const float*)d_in[13];
  const float* oW     = (const float*)d_in[14];
  const float* ob     = (const float*)d_in[15];
  float* out = (float*)d_out;

  char* ws = (char*)d_ws;
  constexpr size_t oWih = 0;                         // 3072x1024 f16
  constexpr size_t oWhh = oWih + 6291456;
  constexpr size_t oCW  = oWhh + 6291456;
  constexpr size_t oOW  = oCW + 6291456;             // 32000x1024 f16
  constexpr size_t oX   = oOW + 65536000;            // 2048x1024 f16
  constexpr size_t oGI  = oX + 4194304;              // 2048x3072 f32
  constexpr size_t oHH0 = oGI + 25165824;            // 64x1024 f16
  constexpr size_t oHH1 = oHH0 + 131072;
  constexpr size_t oCAT = oHH1 + 131072;             // 2048x3072 f16
  constexpr size_t oH2  = oCAT + 12582912;           // 2048x1024 f16
  constexpr size_t oCTR = oH2 + 4194304;             // flags(8KB) + u2/biasS (16KB total)

  f16*   Wih_h = (f16*)(ws + oWih);
  f16*   Whh_h = (f16*)(ws + oWhh);
  f16*   cW_h  = (f16*)(ws + oCW);
  f16*   oW_h  = (f16*)(ws + oOW);
  f16*   X_h   = (f16*)(ws + oX);
  float* GI    = (float*)(ws + oGI);
  f16*   HH0   = (f16*)(ws + oHH0);
  f16*   HH1   = (f16*)(ws + oHH1);
  f16*   CAT   = (f16*)(ws + oCAT);
  f16*   H2    = (f16*)(ws + oH2);
  unsigned int* CTR = (unsigned int*)(ws + oCTR);
  float* U2    = (float*)(CTR + C_U2);
  float* BS    = (float*)(CTR + C_BS);

  constexpr size_t oHidden = (size_t)kM * kV;        // 65,536,000
  constexpr size_t oUW = oHidden + (size_t)kB * kH;
  constexpr size_t oBW = oUW + (size_t)kB * kN * kT;

  // counter/u2 reset, then fused pre-pass (atomicAdds into zeroed CTR page)
  (void)hipMemsetAsync(CTR, 0, 16384, stream);
  pre_kernel<<<709, 256, 0, stream>>>(W_ih, Wih_h, W_hh, Whh_h, seq, emb, X_h,
                                      lh, HH0, attn_W, attn_b, attn_v, CTR);

  // gi = x @ W_ih^T + b_ih
  gemm_bt_kernel<false, float><<<dim3(16, 24), 256, 0, stream>>>(X_h, Wih_h, b_ih, GI, kM, k3H, kH);

  // MEGA: gru recurrence || attention || oW/cW converts   (R5-proven, padded flags)
  mega_kernel<<<kMegaBlks, 256, 0, stream>>>(Whh_h, b_hh, GI, lh, HH0, HH1, CAT,
                                             out + oHidden, CTR,
                                             enc0, enc1, U2, BS,
                                             out + oUW, out + oBW,
                                             oW, oW_h, cW, cW_h);

  // h = tanh(cat @ concat_W^T + concat_b)
  gemm_bt_kernel<true, f16><<<dim3(16, 8), 256, 0, stream>>>(CAT, cW_h, cb, H2, kM, kH, k3H);
  // output = h @ out_W^T + out_b   (proven 128x128, occupancy hint 4 blocks/CU)
  gemm_bt_kernel<false, float><<<dim3(16, 250), 256, 0, stream>>>(H2, oW_h, ob, out, kM, kV, kH);
}